// Round 4
// baseline (167.557 us; speedup 1.0000x reference)
//
#include <hip/hip_runtime.h>
#include <hip/hip_bf16.h>
#include <math.h>

#define NROWS 8192
#define DDIM  128
#define JCHUNKS 32
#define JPER  (NROWS / JCHUNKS)        // 256 cols per chunk
#define NCT   (JPER / 16)              // 16 col-tiles of 16
#define ROWS_PER_BLOCK 128             // 4 waves x 32 rows
#define GRIDX (NROWS / ROWS_PER_BLOCK) // 64
#define LOG2E 1.44269504088896f

typedef __attribute__((ext_vector_type(8))) short bf16x8;  // 8 bf16 = 4 VGPRs
typedef __attribute__((ext_vector_type(4))) float f32x4;
typedef __attribute__((ext_vector_type(2))) float f32x2;

// ---------------- kernel 1: L2 row-normalize -> bf16 ----------------
__global__ __launch_bounds__(256) void norm_kernel(
    const float* __restrict__ f1, const float* __restrict__ f2,
    __hip_bfloat16* __restrict__ f1b, __hip_bfloat16* __restrict__ f2b) {
  int t = threadIdx.x;
  int rloc = t >> 5;                 // 0..7
  int l = t & 31;
  int b = blockIdx.x;                // 0..2047
  int half = (b >= NROWS / 8) ? 1 : 0;
  int row = (b - half * (NROWS / 8)) * 8 + rloc;
  const float* src = half ? f2 : f1;
  __hip_bfloat16* dst = half ? f2b : f1b;

  float4 v = ((const float4*)src)[row * (DDIM / 4) + l];
  float s = v.x * v.x + v.y * v.y + v.z * v.z + v.w * v.w;
  #pragma unroll
  for (int off = 1; off < 32; off <<= 1) s += __shfl_xor(s, off, 64);
  float inv = 1.0f / fmaxf(sqrtf(s), 1e-12f);
  __hip_bfloat16 hv[4];
  hv[0] = __float2bfloat16(v.x * inv);
  hv[1] = __float2bfloat16(v.y * inv);
  hv[2] = __float2bfloat16(v.z * inv);
  hv[3] = __float2bfloat16(v.w * inv);
  *(ushort4*)&dst[(size_t)row * DDIM + l * 4] = *(ushort4*)hv;
}

// ---------------- kernel 2: MFMA cos grid + fused packed stats ----------------
// per-row stats planar: partials[(chunk*4 + s)*NROWS + row], s in {Z, Zp, Cp, Np}
__global__ __launch_bounds__(256, 4) void stats_kernel(
    const __hip_bfloat16* __restrict__ f1b,
    const __hip_bfloat16* __restrict__ f2b,
    const float* __restrict__ targets,
    float* __restrict__ partials) {
  const int chunk = blockIdx.y;                  // 0..31
  const int i0 = blockIdx.x * ROWS_PER_BLOCK;
  const int w    = threadIdx.x >> 6;
  const int lane = threadIdx.x & 63;
  const int l15  = lane & 15;
  const int quad = lane >> 4;
  const int rbase = i0 + w * 32;

  // A fragments resident for whole sweep: A[m=lane&15][k=quad*8+j]
  bf16x8 afrag[2][4];
  #pragma unroll
  for (int rs = 0; rs < 2; ++rs) {
    const __hip_bfloat16* arow =
        &f1b[(size_t)(rbase + rs * 16 + l15) * DDIM + quad * 8];
    #pragma unroll
    for (int ks = 0; ks < 4; ++ks)
      afrag[rs][ks] = *(const bf16x8*)(arow + ks * 32);
  }

  // lane's C rows: comp0 = quad*4+rr, comp1 = 16+quad*4+rr
  f32x2 ti2[4];
  #pragma unroll
  for (int rr = 0; rr < 4; ++rr) {
    ti2[rr][0] = targets[rbase + quad * 4 + rr];
    ti2[rr][1] = targets[rbase + 16 + quad * 4 + rr];
  }

  f32x2 Z2[4]  = {{0,0},{0,0},{0,0},{0,0}};
  f32x2 Zp2[4] = {{0,0},{0,0},{0,0},{0,0}};
  f32x2 Cp2[4] = {{0,0},{0,0},{0,0},{0,0}};
  f32x2 Np2[4] = {{0,0},{0,0},{0,0},{0,0}};

  const int jb0 = chunk * JPER;
  const __hip_bfloat16* bbase = &f2b[(size_t)(jb0 + l15) * DDIM + quad * 8];

  // parity-double-buffered B fragments + tj; no copies, no conditionals
  bf16x8 bbuf[2][4];
  float  tjb[2];

  #pragma unroll
  for (int ks = 0; ks < 4; ++ks)
    bbuf[0][ks] = *(const bf16x8*)(bbase + ks * 32);
  tjb[0] = targets[jb0 + l15];

  #pragma unroll
  for (int ct = 0; ct < NCT; ++ct) {
    const int cur = ct & 1;
    const int nxt = cur ^ 1;

    // issue prefetch for tile ct+1 (wrapped on last iter; result unused) FIRST
    {
      const int ctn = (ct + 1) & (NCT - 1);
      const __hip_bfloat16* src = bbase + (size_t)ctn * 16 * DDIM;
      #pragma unroll
      for (int ks = 0; ks < 4; ++ks)
        bbuf[nxt][ks] = *(const bf16x8*)(src + ks * 32);
      tjb[nxt] = targets[jb0 + ctn * 16 + l15];
    }

    f32x4 acc0 = {0.f, 0.f, 0.f, 0.f};
    f32x4 acc1 = {0.f, 0.f, 0.f, 0.f};
    #pragma unroll
    for (int ks = 0; ks < 4; ++ks) {
      acc0 = __builtin_amdgcn_mfma_f32_16x16x32_bf16(afrag[0][ks], bbuf[cur][ks], acc0, 0, 0, 0);
      acc1 = __builtin_amdgcn_mfma_f32_16x16x32_bf16(afrag[1][ks], bbuf[cur][ks], acc1, 0, 0, 0);
    }

    const float tj = tjb[cur];
    const bool pj = tj > 0.0f;
    const f32x2 tjs = {tj, tj};
    const f32x2 Ks = {LOG2E, LOG2E};
    #pragma unroll
    for (int rr = 0; rr < 4; ++rr) {
      f32x2 c2 = {acc0[rr], acc1[rr]};
      f32x2 d2 = ti2[rr] - tjs;
      bool q0 = (__builtin_fabsf(d2[0]) <= 0.1f) & ((ti2[rr][0] > 0.0f) == pj);
      bool q1 = (__builtin_fabsf(d2[1]) <= 0.1f) & ((ti2[rr][1] > 0.0f) == pj);
      f32x2 m2 = {q0 ? 1.0f : 0.0f, q1 ? 1.0f : 0.0f};
      f32x2 x2 = c2 * Ks - Ks;
      f32x2 e2 = {__builtin_amdgcn_exp2f(x2[0]), __builtin_amdgcn_exp2f(x2[1])};
      Z2[rr]  += e2;
      Zp2[rr] += m2 * e2;
      Cp2[rr] += m2 * c2;
      Np2[rr] += m2;
    }
  }

  // reduce over the 16 lanes (l15) sharing each row
  #pragma unroll
  for (int rr = 0; rr < 4; ++rr) {
    for (int off = 1; off < 16; off <<= 1) {
      Z2[rr][0]  += __shfl_xor(Z2[rr][0],  off, 64);
      Z2[rr][1]  += __shfl_xor(Z2[rr][1],  off, 64);
      Zp2[rr][0] += __shfl_xor(Zp2[rr][0], off, 64);
      Zp2[rr][1] += __shfl_xor(Zp2[rr][1], off, 64);
      Cp2[rr][0] += __shfl_xor(Cp2[rr][0], off, 64);
      Cp2[rr][1] += __shfl_xor(Cp2[rr][1], off, 64);
      Np2[rr][0] += __shfl_xor(Np2[rr][0], off, 64);
      Np2[rr][1] += __shfl_xor(Np2[rr][1], off, 64);
    }
  }
  if (l15 == 0) {
    #pragma unroll
    for (int rs = 0; rs < 2; ++rs)
      #pragma unroll
      for (int rr = 0; rr < 4; ++rr) {
        size_t row = rbase + rs * 16 + quad * 4 + rr;
        size_t cb = (size_t)chunk * 4 * NROWS;
        partials[cb + 0 * NROWS + row] = Z2[rr][rs];
        partials[cb + 1 * NROWS + row] = Zp2[rr][rs];
        partials[cb + 2 * NROWS + row] = Cp2[rr][rs];
        partials[cb + 3 * NROWS + row] = Np2[rr][rs];
      }
  }
}

// ---------------- kernel 3: per-row loss + global mean (atomic) ----------------
__global__ void finalize_rows(const float* __restrict__ partials,
                              float* __restrict__ out) {
  int r = blockIdx.x * 256 + threadIdx.x;   // grid 32 x 256
  float Z = 0, Zp = 0, Cp = 0, Np = 0;
  for (int ch = 0; ch < JCHUNKS; ++ch) {
    const float* cb = partials + (size_t)ch * 4 * NROWS;
    Z  += cb[0 * NROWS + r];
    Zp += cb[1 * NROWS + r];
    Cp += cb[2 * NROWS + r];
    Np += cb[3 * NROWS + r];
  }
  float Zn = Z - Zp;
  float nn = (float)NROWS - Np;
  float spos = (1.0f + logf(Z)) - Cp / Np;
  float sneg = Zn / Z - nn * 1e-10f;
  float per_row = spos + sneg / nn;

  float v = per_row;
  for (int off = 32; off; off >>= 1) v += __shfl_xor(v, off, 64);
  __shared__ float wsum[4];
  int lane = threadIdx.x & 63, wid = threadIdx.x >> 6;
  if (lane == 0) wsum[wid] = v;
  __syncthreads();
  if (threadIdx.x == 0)
    atomicAdd(out, (wsum[0] + wsum[1] + wsum[2] + wsum[3]) * (1.0f / (float)NROWS));
}

// ---------------- launch ----------------
extern "C" void kernel_launch(void* const* d_in, const int* in_sizes, int n_in,
                              void* d_out, int out_size, void* d_ws, size_t ws_size,
                              hipStream_t stream) {
  const float* f1  = (const float*)d_in[0];
  const float* f2  = (const float*)d_in[1];
  const float* tgt = (const float*)d_in[2];
  float* out = (float*)d_out;

  char* ws = (char*)d_ws;
  __hip_bfloat16* f1b = (__hip_bfloat16*)ws;                       // 2 MB
  __hip_bfloat16* f2b = (__hip_bfloat16*)(ws + (size_t)NROWS * DDIM * 2);
  float* partials = (float*)(ws + (size_t)NROWS * DDIM * 4);       // 32*4*8192 floats = 4 MB

  hipMemsetAsync(out, 0, sizeof(float), stream);
  norm_kernel<<<2 * (NROWS / 8), 256, 0, stream>>>(f1, f2, f1b, f2b);
  dim3 g2(GRIDX, JCHUNKS);
  stats_kernel<<<g2, 256, 0, stream>>>(f1b, f2b, tgt, partials);
  finalize_rows<<<NROWS / 256, 256, 0, stream>>>(partials, out);
}

// Round 5
// 103.974 us; speedup vs baseline: 1.6115x; 1.6115x over previous
//
#include <hip/hip_runtime.h>
#include <hip/hip_bf16.h>
#include <math.h>

#define NROWS 8192
#define DDIM  128
#define JCHUNKS 16
#define JPER  (NROWS / JCHUNKS)        // 512 cols per chunk
#define STAGE_COLS 64
#define NSTAGES (JPER / STAGE_COLS)    // 8
#define ROWS_PER_BLOCK 128             // 4 waves x 32 rows
#define GRIDX (NROWS / ROWS_PER_BLOCK) // 64
#define LOG2E 1.44269504088896f

#define AS1 __attribute__((address_space(1)))
#define AS3 __attribute__((address_space(3)))

typedef __attribute__((ext_vector_type(8))) short bf16x8;  // 8 bf16 = 4 VGPRs
typedef __attribute__((ext_vector_type(4))) float f32x4;
typedef __attribute__((ext_vector_type(2))) float f32x2;

// ---------------- kernel 1: L2 row-normalize -> bf16 ----------------
__global__ __launch_bounds__(256) void norm_kernel(
    const float* __restrict__ f1, const float* __restrict__ f2,
    __hip_bfloat16* __restrict__ f1b, __hip_bfloat16* __restrict__ f2b) {
  int t = threadIdx.x;
  int rloc = t >> 5;                 // 0..7
  int l = t & 31;
  int b = blockIdx.x;                // 0..2047
  int half = (b >= NROWS / 8) ? 1 : 0;
  int row = (b - half * (NROWS / 8)) * 8 + rloc;
  const float* src = half ? f2 : f1;
  __hip_bfloat16* dst = half ? f2b : f1b;

  float4 v = ((const float4*)src)[row * (DDIM / 4) + l];
  float s = v.x * v.x + v.y * v.y + v.z * v.z + v.w * v.w;
  #pragma unroll
  for (int off = 1; off < 32; off <<= 1) s += __shfl_xor(s, off, 64);
  float inv = 1.0f / fmaxf(sqrtf(s), 1e-12f);
  __hip_bfloat16 hv[4];
  hv[0] = __float2bfloat16(v.x * inv);
  hv[1] = __float2bfloat16(v.y * inv);
  hv[2] = __float2bfloat16(v.z * inv);
  hv[3] = __float2bfloat16(v.w * inv);
  *(ushort4*)&dst[(size_t)row * DDIM + l * 4] = *(ushort4*)hv;
}

// ---------------- kernel 2: MFMA cos grid, LDS-staged B, fused stats ----------------
// partials[(row*JCHUNKS + chunk)*4 + {Z,Zp,Cp,Np}]
__global__ __launch_bounds__(256, 4) void stats_kernel(
    const __hip_bfloat16* __restrict__ f1b,
    const __hip_bfloat16* __restrict__ f2b,
    const float* __restrict__ targets,
    float* __restrict__ partials) {
  // two single-stage B buffers: 64 rows x 256 B, XOR-swizzled chunks
  __shared__ __align__(16) char lds0[STAGE_COLS * 256];
  __shared__ __align__(16) char lds1[STAGE_COLS * 256];

  const int chunk = blockIdx.y;                  // 0..15
  const int i0 = blockIdx.x * ROWS_PER_BLOCK;
  const int w    = threadIdx.x >> 6;
  const int lane = threadIdx.x & 63;
  const int p15  = lane & 15;                    // n / chunk id
  const int rl4  = lane >> 4;                    // quad
  const int rbase = i0 + w * 32;

  // ---- A fragments resident for whole sweep: A[m=lane&15][k=quad*8+j] ----
  bf16x8 afrag[2][4];
  #pragma unroll
  for (int rs = 0; rs < 2; ++rs) {
    const __hip_bfloat16* arow =
        &f1b[(size_t)(rbase + rs * 16 + p15) * DDIM + rl4 * 8];
    #pragma unroll
    for (int ks = 0; ks < 4; ++ks)
      afrag[rs][ks] = *(const bf16x8*)(arow + ks * 32);
  }

  // lane's C rows: comp0 = quad*4+rr, comp1 = 16+quad*4+rr
  f32x2 ti2[4];
  #pragma unroll
  for (int rr = 0; rr < 4; ++rr) {
    ti2[rr][0] = targets[rbase + rl4 * 4 + rr];
    ti2[rr][1] = targets[rbase + 16 + rl4 * 4 + rr];
  }

  f32x2 Z2[4]  = {{0,0},{0,0},{0,0},{0,0}};
  f32x2 Zp2[4] = {{0,0},{0,0},{0,0},{0,0}};
  f32x2 Cp2[4] = {{0,0},{0,0},{0,0},{0,0}};
  f32x2 Np2[4] = {{0,0},{0,0},{0,0},{0,0}};

  const int jb0 = chunk * JPER;

  // ---- DMA source offsets (elements) within a 64-row stage block ----
  // round q: row = w*16 + q*4 + rl4 ; source chunk = p15 ^ (q*4 + rl4)
  // (LDS phys chunk = p15; content chunk c stored at phys c ^ (row&15))
  int srcoff[4];
  #pragma unroll
  for (int q = 0; q < 4; ++q) {
    int rloc = w * 16 + q * 4 + rl4;
    int c    = p15 ^ (q * 4 + rl4);
    srcoff[q] = rloc * DDIM + c * 8;
  }

  // prologue: DMA stage 0 -> lds0
  {
    const __hip_bfloat16* gstage = f2b + (size_t)jb0 * DDIM;
    char* lbase = &lds0[w * 4096];
    #pragma unroll
    for (int q = 0; q < 4; ++q)
      __builtin_amdgcn_global_load_lds((const AS1 void*)(gstage + srcoff[q]),
                                       (AS3 void*)(lbase + q * 1024), 16, 0, 0);
  }

  for (int s = 0; s < NSTAGES; ++s) {
    __syncthreads();   // stage-s DMA complete; buf[(s+1)&1] free to overwrite

    // issue DMA for stage s+1
    if (s + 1 < NSTAGES) {
      const __hip_bfloat16* gstage = f2b + (size_t)(jb0 + (s + 1) * STAGE_COLS) * DDIM;
      char* lbase = ((s + 1) & 1) ? &lds1[w * 4096] : &lds0[w * 4096];
      #pragma unroll
      for (int q = 0; q < 4; ++q)
        __builtin_amdgcn_global_load_lds((const AS1 void*)(gstage + srcoff[q]),
                                         (AS3 void*)(lbase + q * 1024), 16, 0, 0);
    }

    const char* lb = (s & 1) ? lds1 : lds0;
    #pragma unroll
    for (int ct = 0; ct < 4; ++ct) {
      const int rloc = ct * 16 + p15;            // B row (col index n) in stage
      // swizzled fragment reads: conflict-free ds_read_b128
      bf16x8 bfrag[4];
      #pragma unroll
      for (int ks = 0; ks < 4; ++ks)
        bfrag[ks] = *(const bf16x8*)(lb + rloc * 256 + (((rl4 + ks * 4) ^ p15) << 4));

      float tj = targets[jb0 + s * STAGE_COLS + ct * 16 + p15];

      f32x4 acc0 = {0.f, 0.f, 0.f, 0.f};
      f32x4 acc1 = {0.f, 0.f, 0.f, 0.f};
      #pragma unroll
      for (int ks = 0; ks < 4; ++ks) {
        acc0 = __builtin_amdgcn_mfma_f32_16x16x32_bf16(afrag[0][ks], bfrag[ks], acc0, 0, 0, 0);
        acc1 = __builtin_amdgcn_mfma_f32_16x16x32_bf16(afrag[1][ks], bfrag[ks], acc1, 0, 0, 0);
      }

      const bool pj = tj > 0.0f;
      const f32x2 tjs = {tj, tj};
      const f32x2 Ks = {LOG2E, LOG2E};
      #pragma unroll
      for (int rr = 0; rr < 4; ++rr) {
        f32x2 c2 = {acc0[rr], acc1[rr]};
        f32x2 d2 = ti2[rr] - tjs;
        bool q0 = (__builtin_fabsf(d2[0]) <= 0.1f) & ((ti2[rr][0] > 0.0f) == pj);
        bool q1 = (__builtin_fabsf(d2[1]) <= 0.1f) & ((ti2[rr][1] > 0.0f) == pj);
        f32x2 m2 = {q0 ? 1.0f : 0.0f, q1 ? 1.0f : 0.0f};
        f32x2 x2 = c2 * Ks - Ks;
        f32x2 e2 = {__builtin_amdgcn_exp2f(x2[0]), __builtin_amdgcn_exp2f(x2[1])};
        Z2[rr]  += e2;
        Zp2[rr] += m2 * e2;
        Cp2[rr] += m2 * c2;
        Np2[rr] += m2;
      }
    }
  }

  // reduce over the 16 lanes (p15) sharing each row
  #pragma unroll
  for (int rr = 0; rr < 4; ++rr) {
    for (int off = 1; off < 16; off <<= 1) {
      Z2[rr][0]  += __shfl_xor(Z2[rr][0],  off, 64);
      Z2[rr][1]  += __shfl_xor(Z2[rr][1],  off, 64);
      Zp2[rr][0] += __shfl_xor(Zp2[rr][0], off, 64);
      Zp2[rr][1] += __shfl_xor(Zp2[rr][1], off, 64);
      Cp2[rr][0] += __shfl_xor(Cp2[rr][0], off, 64);
      Cp2[rr][1] += __shfl_xor(Cp2[rr][1], off, 64);
      Np2[rr][0] += __shfl_xor(Np2[rr][0], off, 64);
      Np2[rr][1] += __shfl_xor(Np2[rr][1], off, 64);
    }
  }
  if (p15 == 0) {
    #pragma unroll
    for (int rs = 0; rs < 2; ++rs)
      #pragma unroll
      for (int rr = 0; rr < 4; ++rr) {
        size_t row = rbase + rs * 16 + rl4 * 4 + rr;
        f32x4 st = {Z2[rr][rs], Zp2[rr][rs], Cp2[rr][rs], Np2[rr][rs]};
        *(f32x4*)&partials[((size_t)row * JCHUNKS + chunk) * 4] = st;
      }
  }
}

// ---------------- kernel 3: per-row loss + global mean (atomic) ----------------
__global__ void finalize_rows(const float* __restrict__ partials,
                              float* __restrict__ out) {
  int r = blockIdx.x * 256 + threadIdx.x;   // grid 32 x 256
  float Z = 0, Zp = 0, Cp = 0, Np = 0;
  for (int ch = 0; ch < JCHUNKS; ++ch) {
    float4 p = *(const float4*)&partials[((size_t)r * JCHUNKS + ch) * 4];
    Z += p.x; Zp += p.y; Cp += p.z; Np += p.w;
  }
  float Zn = Z - Zp;
  float nn = (float)NROWS - Np;
  float spos = (1.0f + logf(Z)) - Cp / Np;
  float sneg = Zn / Z - nn * 1e-10f;
  float per_row = spos + sneg / nn;

  float v = per_row;
  for (int off = 32; off; off >>= 1) v += __shfl_xor(v, off, 64);
  __shared__ float wsum[4];
  int lane = threadIdx.x & 63, wid = threadIdx.x >> 6;
  if (lane == 0) wsum[wid] = v;
  __syncthreads();
  if (threadIdx.x == 0)
    atomicAdd(out, (wsum[0] + wsum[1] + wsum[2] + wsum[3]) * (1.0f / (float)NROWS));
}

// ---------------- launch ----------------
extern "C" void kernel_launch(void* const* d_in, const int* in_sizes, int n_in,
                              void* d_out, int out_size, void* d_ws, size_t ws_size,
                              hipStream_t stream) {
  const float* f1  = (const float*)d_in[0];
  const float* f2  = (const float*)d_in[1];
  const float* tgt = (const float*)d_in[2];
  float* out = (float*)d_out;

  char* ws = (char*)d_ws;
  __hip_bfloat16* f1b = (__hip_bfloat16*)ws;                       // 2 MB
  __hip_bfloat16* f2b = (__hip_bfloat16*)(ws + (size_t)NROWS * DDIM * 2);
  float* partials = (float*)(ws + (size_t)NROWS * DDIM * 4);       // 8192*16*4 floats = 2 MB

  hipMemsetAsync(out, 0, sizeof(float), stream);
  norm_kernel<<<2 * (NROWS / 8), 256, 0, stream>>>(f1, f2, f1b, f2b);
  dim3 g2(GRIDX, JCHUNKS);
  stats_kernel<<<g2, 256, 0, stream>>>(f1b, f2b, tgt, partials);
  finalize_rows<<<NROWS / 256, 256, 0, stream>>>(partials, out);
}

// Round 6
// 100.755 us; speedup vs baseline: 1.6630x; 1.0319x over previous
//
#include <hip/hip_runtime.h>
#include <hip/hip_bf16.h>
#include <math.h>

#define NROWS 8192
#define DDIM  128
#define JCHUNKS 16
#define JPER  (NROWS / JCHUNKS)        // 512 cols per chunk
#define STAGE_COLS 64
#define NSTAGES (JPER / STAGE_COLS)    // 8
#define ROWS_PER_BLOCK 128             // 4 waves x 32 rows
#define GRIDX (NROWS / ROWS_PER_BLOCK) // 64
#define LOG2E 1.44269504088896f

#define AS1 __attribute__((address_space(1)))
#define AS3 __attribute__((address_space(3)))

typedef __attribute__((ext_vector_type(8))) short bf16x8;  // 8 bf16 = 4 VGPRs
typedef __attribute__((ext_vector_type(4))) float f32x4;
typedef __attribute__((ext_vector_type(2))) float f32x2;

// ---------------- kernel 1: L2 row-normalize -> bf16 (also zeroes out[0]) ----------------
__global__ __launch_bounds__(256) void norm_kernel(
    const float* __restrict__ f1, const float* __restrict__ f2,
    __hip_bfloat16* __restrict__ f1b, __hip_bfloat16* __restrict__ f2b,
    float* __restrict__ out) {
  if (blockIdx.x == 0 && threadIdx.x == 0) out[0] = 0.0f;  // stream-ordered before finalize
  int t = threadIdx.x;
  int rloc = t >> 5;                 // 0..7
  int l = t & 31;
  int b = blockIdx.x;                // 0..2047
  int half = (b >= NROWS / 8) ? 1 : 0;
  int row = (b - half * (NROWS / 8)) * 8 + rloc;
  const float* src = half ? f2 : f1;
  __hip_bfloat16* dst = half ? f2b : f1b;

  float4 v = ((const float4*)src)[row * (DDIM / 4) + l];
  float s = v.x * v.x + v.y * v.y + v.z * v.z + v.w * v.w;
  #pragma unroll
  for (int off = 1; off < 32; off <<= 1) s += __shfl_xor(s, off, 64);
  float inv = 1.0f / fmaxf(sqrtf(s), 1e-12f);
  __hip_bfloat16 hv[4];
  hv[0] = __float2bfloat16(v.x * inv);
  hv[1] = __float2bfloat16(v.y * inv);
  hv[2] = __float2bfloat16(v.z * inv);
  hv[3] = __float2bfloat16(v.w * inv);
  *(ushort4*)&dst[(size_t)row * DDIM + l * 4] = *(ushort4*)hv;
}

// ---------------- kernel 2: MFMA cos grid, LDS-staged B + targets, fused stats ----------------
// partials[(row*JCHUNKS + chunk)*4 + {Z,Zp,Cp,Np}]
__global__ __launch_bounds__(256, 4) void stats_kernel(
    const __hip_bfloat16* __restrict__ f1b,
    const __hip_bfloat16* __restrict__ f2b,
    const float* __restrict__ targets,
    float* __restrict__ partials) {
  __shared__ __align__(16) char lds0[STAGE_COLS * 256];   // 16 KB
  __shared__ __align__(16) char lds1[STAGE_COLS * 256];   // 16 KB
  __shared__ __align__(16) float tsh[JPER];               // 2 KB: chunk's targets

  const int chunk = blockIdx.y;                  // 0..15
  const int i0 = blockIdx.x * ROWS_PER_BLOCK;
  const int w    = threadIdx.x >> 6;
  const int lane = threadIdx.x & 63;
  const int p15  = lane & 15;
  const int rl4  = lane >> 4;                    // quad
  const int rbase = i0 + w * 32;

  // ---- A fragments resident for whole sweep: A[m=lane&15][k=quad*8+j] ----
  bf16x8 afrag[2][4];
  #pragma unroll
  for (int rs = 0; rs < 2; ++rs) {
    const __hip_bfloat16* arow =
        &f1b[(size_t)(rbase + rs * 16 + p15) * DDIM + rl4 * 8];
    #pragma unroll
    for (int ks = 0; ks < 4; ++ks)
      afrag[rs][ks] = *(const bf16x8*)(arow + ks * 32);
  }

  // lane's C rows: comp0 = quad*4+rr, comp1 = 16+quad*4+rr
  f32x2 ti2[4];
  #pragma unroll
  for (int rr = 0; rr < 4; ++rr) {
    ti2[rr][0] = targets[rbase + rl4 * 4 + rr];
    ti2[rr][1] = targets[rbase + 16 + rl4 * 4 + rr];
  }

  f32x2 Z2[4]  = {{0,0},{0,0},{0,0},{0,0}};
  f32x2 Zp2[4] = {{0,0},{0,0},{0,0},{0,0}};
  f32x2 Cp2[4] = {{0,0},{0,0},{0,0},{0,0}};
  f32x2 Np2[4] = {{0,0},{0,0},{0,0},{0,0}};

  const int jb0 = chunk * JPER;

  // ---- DMA source offsets (elements) within a 64-row stage block ----
  int srcoff[4];
  #pragma unroll
  for (int q = 0; q < 4; ++q) {
    int rloc = w * 16 + q * 4 + rl4;
    int c    = p15 ^ (q * 4 + rl4);
    srcoff[q] = rloc * DDIM + c * 8;
  }

  // prologue: DMA targets chunk (2 rounds) + stage 0 -> lds0
  {
    #pragma unroll
    for (int rnd = 0; rnd < 2; ++rnd)
      __builtin_amdgcn_global_load_lds(
          (const AS1 void*)(targets + jb0 + rnd * 256 + w * 64 + lane),
          (AS3 void*)(&tsh[rnd * 256 + w * 64]), 4, 0, 0);
    const __hip_bfloat16* gstage = f2b + (size_t)jb0 * DDIM;
    char* lbase = &lds0[w * 4096];
    #pragma unroll
    for (int q = 0; q < 4; ++q)
      __builtin_amdgcn_global_load_lds((const AS1 void*)(gstage + srcoff[q]),
                                       (AS3 void*)(lbase + q * 1024), 16, 0, 0);
  }

  for (int s = 0; s < NSTAGES; ++s) {
    __syncthreads();   // stage-s DMA complete; buf[(s+1)&1] free to overwrite

    if (s + 1 < NSTAGES) {
      const __hip_bfloat16* gstage = f2b + (size_t)(jb0 + (s + 1) * STAGE_COLS) * DDIM;
      char* lbase = ((s + 1) & 1) ? &lds1[w * 4096] : &lds0[w * 4096];
      #pragma unroll
      for (int q = 0; q < 4; ++q)
        __builtin_amdgcn_global_load_lds((const AS1 void*)(gstage + srcoff[q]),
                                         (AS3 void*)(lbase + q * 1024), 16, 0, 0);
    }

    const char* lb = (s & 1) ? lds1 : lds0;
    #pragma unroll
    for (int ct = 0; ct < 4; ++ct) {
      const int rloc = ct * 16 + p15;            // B row (col index n) in stage
      bf16x8 bfrag[4];
      #pragma unroll
      for (int ks = 0; ks < 4; ++ks)
        bfrag[ks] = *(const bf16x8*)(lb + rloc * 256 + (((rl4 + ks * 4) ^ p15) << 4));

      float tj = tsh[s * STAGE_COLS + ct * 16 + p15];  // broadcast within quad: conflict-free

      f32x4 acc0 = {0.f, 0.f, 0.f, 0.f};
      f32x4 acc1 = {0.f, 0.f, 0.f, 0.f};
      #pragma unroll
      for (int ks = 0; ks < 4; ++ks) {
        acc0 = __builtin_amdgcn_mfma_f32_16x16x32_bf16(afrag[0][ks], bfrag[ks], acc0, 0, 0, 0);
        acc1 = __builtin_amdgcn_mfma_f32_16x16x32_bf16(afrag[1][ks], bfrag[ks], acc1, 0, 0, 0);
      }

      const bool pj = tj > 0.0f;
      const f32x2 tjs = {tj, tj};
      const f32x2 Ks = {LOG2E, LOG2E};
      #pragma unroll
      for (int rr = 0; rr < 4; ++rr) {
        f32x2 c2 = {acc0[rr], acc1[rr]};
        f32x2 d2 = ti2[rr] - tjs;
        bool q0 = (__builtin_fabsf(d2[0]) <= 0.1f) & ((ti2[rr][0] > 0.0f) == pj);
        bool q1 = (__builtin_fabsf(d2[1]) <= 0.1f) & ((ti2[rr][1] > 0.0f) == pj);
        f32x2 m2 = {q0 ? 1.0f : 0.0f, q1 ? 1.0f : 0.0f};
        f32x2 x2 = c2 * Ks - Ks;
        f32x2 e2 = {__builtin_amdgcn_exp2f(x2[0]), __builtin_amdgcn_exp2f(x2[1])};
        Z2[rr]  += e2;
        Zp2[rr] += m2 * e2;
        Cp2[rr] += m2 * c2;
        Np2[rr] += m2;
      }
    }
  }

  // reduce over the 16 lanes (p15) sharing each row
  #pragma unroll
  for (int rr = 0; rr < 4; ++rr) {
    for (int off = 1; off < 16; off <<= 1) {
      Z2[rr][0]  += __shfl_xor(Z2[rr][0],  off, 64);
      Z2[rr][1]  += __shfl_xor(Z2[rr][1],  off, 64);
      Zp2[rr][0] += __shfl_xor(Zp2[rr][0], off, 64);
      Zp2[rr][1] += __shfl_xor(Zp2[rr][1], off, 64);
      Cp2[rr][0] += __shfl_xor(Cp2[rr][0], off, 64);
      Cp2[rr][1] += __shfl_xor(Cp2[rr][1], off, 64);
      Np2[rr][0] += __shfl_xor(Np2[rr][0], off, 64);
      Np2[rr][1] += __shfl_xor(Np2[rr][1], off, 64);
    }
  }
  if (p15 == 0) {
    #pragma unroll
    for (int rs = 0; rs < 2; ++rs)
      #pragma unroll
      for (int rr = 0; rr < 4; ++rr) {
        size_t row = rbase + rs * 16 + rl4 * 4 + rr;
        f32x4 st = {Z2[rr][rs], Zp2[rr][rs], Cp2[rr][rs], Np2[rr][rs]};
        *(f32x4*)&partials[((size_t)row * JCHUNKS + chunk) * 4] = st;
      }
  }
}

// ---------------- kernel 3: per-row loss + global mean (atomic) ----------------
__global__ void finalize_rows(const float* __restrict__ partials,
                              float* __restrict__ out) {
  int r = blockIdx.x * 256 + threadIdx.x;   // grid 32 x 256
  float Z = 0, Zp = 0, Cp = 0, Np = 0;
  for (int ch = 0; ch < JCHUNKS; ++ch) {
    float4 p = *(const float4*)&partials[((size_t)r * JCHUNKS + ch) * 4];
    Z += p.x; Zp += p.y; Cp += p.z; Np += p.w;
  }
  float Zn = Z - Zp;
  float nn = (float)NROWS - Np;
  float spos = (1.0f + logf(Z)) - Cp / Np;
  float sneg = Zn / Z - nn * 1e-10f;
  float per_row = spos + sneg / nn;

  float v = per_row;
  for (int off = 32; off; off >>= 1) v += __shfl_xor(v, off, 64);
  __shared__ float wsum[4];
  int lane = threadIdx.x & 63, wid = threadIdx.x >> 6;
  if (lane == 0) wsum[wid] = v;
  __syncthreads();
  if (threadIdx.x == 0)
    atomicAdd(out, (wsum[0] + wsum[1] + wsum[2] + wsum[3]) * (1.0f / (float)NROWS));
}

// ---------------- launch ----------------
extern "C" void kernel_launch(void* const* d_in, const int* in_sizes, int n_in,
                              void* d_out, int out_size, void* d_ws, size_t ws_size,
                              hipStream_t stream) {
  const float* f1  = (const float*)d_in[0];
  const float* f2  = (const float*)d_in[1];
  const float* tgt = (const float*)d_in[2];
  float* out = (float*)d_out;

  char* ws = (char*)d_ws;
  __hip_bfloat16* f1b = (__hip_bfloat16*)ws;                       // 2 MB
  __hip_bfloat16* f2b = (__hip_bfloat16*)(ws + (size_t)NROWS * DDIM * 2);
  float* partials = (float*)(ws + (size_t)NROWS * DDIM * 4);       // 2 MB

  norm_kernel<<<2 * (NROWS / 8), 256, 0, stream>>>(f1, f2, f1b, f2b, out);
  dim3 g2(GRIDX, JCHUNKS);
  stats_kernel<<<g2, 256, 0, stream>>>(f1b, f2b, tgt, partials);
  finalize_rows<<<NROWS / 256, 256, 0, stream>>>(partials, out);
}